// Round 5
// baseline (174.553 us; speedup 1.0000x reference)
//
#include <hip/hip_runtime.h>
#include <math.h>

#define BB 2
#define NN 1024
#define CC 256
#define NQ 100
#define HALF 128

typedef __attribute__((ext_vector_type(8))) short bf16x8;
typedef __attribute__((ext_vector_type(4))) float f32x4;

// gelu via A&S 7.1.26 erf: |err| <= 3e-7 abs; 1 rcp, no exp.
__device__ __forceinline__ float gelu_fast(float x) {
    float a = fabsf(0.70710678118654752f * x);
    float t = fmaf(a, 4.30638e-5f, 2.765672e-4f);
    t = fmaf(a, t, 1.520143e-4f);
    t = fmaf(a, t, 9.2705272e-3f);
    t = fmaf(a, t, 4.22820123e-2f);
    t = fmaf(a, t, 7.05230784e-2f);
    float p = fmaf(a, t, 1.0f);
    float p2 = p * p;
    float p4 = p2 * p2;
    float p8 = p4 * p4;
    float p16 = p8 * p8;
    float r = 0.5f * __builtin_amdgcn_rcpf(p16);   // 0.5*(1-erf(a))
    float phi = (x >= 0.0f) ? (1.0f - r) : r;
    return x * phi;
}

__device__ __forceinline__ short f2bf(float f) {
    union { float f; unsigned u; } v; v.f = f;
    return (short)((v.u + 0x7FFFu + ((v.u >> 16) & 1u)) >> 16);
}

// ---- kA: blocks 0..511: LN -> W_in GEMM -> gelu -> gpart/ppart partial stores
//          -> h_local @ W1[0:128] -> At (MFMA-tiled). 4 rows/block.
//      blocks 512..543: W2 -> bf16 [n][k] transpose. ----
// At layout: At[b][row/16][c/8][row%16][c%8].
__global__ __launch_bounds__(256) void kA_fused(
        const float* __restrict__ x, const float* __restrict__ ln_g,
        const float* __restrict__ ln_b, const float* __restrict__ W_in,
        const float* __restrict__ b_in, const float* __restrict__ policy,
        const float* __restrict__ W1, const float* __restrict__ W2,
        float* __restrict__ At, float* __restrict__ gpart,
        float* __restrict__ ppart, short* __restrict__ W2T) {
    int t = threadIdx.x;
    int blk = blockIdx.x;
    if (blk >= 512) {
        int u = (blk - 512) * 256 + t;
        int c = u >> 6, kg = u & 63;
        short4 v;
        v.x = f2bf(W2[(kg * 4 + 0) * HALF + c]);
        v.y = f2bf(W2[(kg * 4 + 1) * HALF + c]);
        v.z = f2bf(W2[(kg * 4 + 2) * HALF + c]);
        v.w = f2bf(W2[(kg * 4 + 3) * HALF + c]);
        *(short4*)(W2T + c * CC + kg * 4) = v;
        return;
    }
    __shared__ float xst[CC][4];
    __shared__ float hst[HALF][4];
    int wave = t >> 6, lane = t & 63;
    int row0 = blk * 4;
    const float* xr = x + (size_t)(row0 + wave) * CC;
    float v0 = xr[lane], v1 = xr[lane + 64], v2 = xr[lane + 128], v3 = xr[lane + 192];
    float s = v0 + v1 + v2 + v3;
    for (int off = 32; off; off >>= 1) s += __shfl_down(s, off);
    s = __shfl(s, 0);
    float mu = s * (1.0f / CC);
    float d0 = v0 - mu, d1 = v1 - mu, d2 = v2 - mu, d3 = v3 - mu;
    float vs = d0 * d0 + d1 * d1 + d2 * d2 + d3 * d3;
    for (int off = 32; off; off >>= 1) vs += __shfl_down(vs, off);
    vs = __shfl(vs, 0);
    float rstd = rsqrtf(vs * (1.0f / CC) + 1e-5f);
    xst[lane][wave]       = d0 * rstd * ln_g[lane]       + ln_b[lane];
    xst[lane + 64][wave]  = d1 * rstd * ln_g[lane + 64]  + ln_b[lane + 64];
    xst[lane + 128][wave] = d2 * rstd * ln_g[lane + 128] + ln_b[lane + 128];
    xst[lane + 192][wave] = d3 * rstd * ln_g[lane + 192] + ln_b[lane + 192];
    __syncthreads();
    // GEMM1: h[row0+r][t] = gelu(LN(x)@W_in + b_in)
    float a0 = b_in[t], a1 = a0, a2 = a0, a3 = a0;
    #pragma unroll 8
    for (int k = 0; k < CC; ++k) {
        float4 xv = *(const float4*)xst[k];     // uniform addr -> broadcast
        float wv = W_in[k * CC + t];
        a0 = fmaf(xv.x, wv, a0); a1 = fmaf(xv.y, wv, a1);
        a2 = fmaf(xv.z, wv, a2); a3 = fmaf(xv.w, wv, a3);
    }
    float h0 = gelu_fast(a0), h1 = gelu_fast(a1), h2 = gelu_fast(a2), h3 = gelu_fast(a3);
    float p0 = policy[row0], p1 = policy[row0 + 1], p2 = policy[row0 + 2], p3 = policy[row0 + 3];
    if (t < HALF) {
        hst[t][0] = h0; hst[t][1] = h1; hst[t][2] = h2; hst[t][3] = h3;
    } else {
        gpart[(size_t)blk * HALF + (t - HALF)] = h0 * p0 + h1 * p1 + h2 * p2 + h3 * p3;
    }
    if (t == 0) ppart[blk] = p0 + p1 + p2 + p3;
    __syncthreads();
    // GEMM2: A[row0+r][t] = h_local[row0+r] @ W1[0:128]
    float c0 = 0, c1 = 0, c2 = 0, c3 = 0;
    #pragma unroll 8
    for (int k = 0; k < HALF; ++k) {
        float4 hv = *(const float4*)hst[k];     // uniform addr -> broadcast
        float wv = W1[k * CC + t];
        c0 = fmaf(hv.x, wv, c0); c1 = fmaf(hv.y, wv, c1);
        c2 = fmaf(hv.z, wv, c2); c3 = fmaf(hv.w, wv, c3);
    }
    int b = row0 >> 10;
    int lr = row0 & (NN - 1);
    size_t tb = ((size_t)(b * 64 + (lr >> 4)) * 32 + (t >> 3)) * 128 + (t & 7);
    int r16 = lr & 15;
    At[tb + (r16 + 0) * 8] = c0;
    At[tb + (r16 + 1) * 8] = c1;
    At[tb + (r16 + 2) * 8] = c2;
    At[tb + (r16 + 3) * 8] = c3;
}

// ---- kB: Qc[b,i] = q@W1[256:512] + glob@W1[128:256] + b1; glob reduced
//          redundantly per block from gpart/ppart (no atomics, no memset). ----
__global__ __launch_bounds__(256) void kB_qc(
        const float* __restrict__ query, const float* __restrict__ W1,
        const float* __restrict__ gpart, const float* __restrict__ ppart,
        const float* __restrict__ b1, float* __restrict__ Qc) {
    __shared__ float gls[HALF];
    __shared__ float qs[CC];
    __shared__ float psS;
    int blk = blockIdx.x, t = threadIdx.x;
    int b = blk / NQ, i = blk % NQ;
    // psum: 256 chunk partials for this b
    if (t < 64) {
        const float* pp = ppart + b * 256;
        float ps = pp[t] + pp[t + 64] + pp[t + 128] + pp[t + 192];
        for (int off = 32; off; off >>= 1) ps += __shfl_down(ps, off);
        if (t == 0) psS = ps;
    }
    // glob numerator: sum 256 chunks, coalesced over t
    if (t < HALF) {
        const float* gp = gpart + (size_t)b * 256 * HALF + t;
        float s = 0.f;
        #pragma unroll 8
        for (int ch = 0; ch < 256; ++ch) s += gp[ch * HALF];
        gls[t] = s;
    }
    qs[t] = query[(size_t)(i * BB + b) * CC + t];
    __syncthreads();
    float inv_ps = 1.0f / psS;
    float g = b1[t];
    #pragma unroll 8
    for (int k = 0; k < HALF; ++k)
        g = fmaf(gls[k] * inv_ps, W1[(HALF + k) * CC + t], g);
    #pragma unroll 8
    for (int k = 0; k < CC; ++k)
        g = fmaf(qs[k], W1[(2 * HALF + k) * CC + t], g);
    Qc[(size_t)blk * CC + t] = g;
}

// ---- k5: in-register z1 frags from tiled At -> MFMA vs dbuf-LDS W2 -> gelu
//          -> W3 -> log_softmax. Block M=64, N=128; wave-tile 16x128. ----
// K chunked at 32 (8 chunks), double-buffered: 2 x 128 x W2S shorts.
#define W2S 40   // 80 B row stride

__global__ __launch_bounds__(256, 6) void k5_main(
        const float* __restrict__ At, const float* __restrict__ Qc,
        const short* __restrict__ W2T, const float* __restrict__ b2,
        const float* __restrict__ W3, const float* __restrict__ b3,
        float* __restrict__ out) {
    __shared__ short w2s[2][128 * W2S];   // 2 x 10240 B

    int t = threadIdx.x;
    int lane = t & 63, w = t >> 6;
    int col16 = lane & 15, quad = lane >> 4;
    int blk = blockIdx.x;
    int jt = blk & 15;
    int iq = (blk >> 4) % NQ;
    int b  = blk / (16 * NQ);
    const float* Abase = At + ((size_t)(b * 64 + jt * 4 + w) * 32) * 128 + col16 * 8;
    const float* Qrow = Qc + (size_t)(b * NQ + iq) * CC;

    // staging indices: u = e*256+t, n = u>>2 (0..127), kg = u&3
    int sn = t >> 2, skg = t & 3;
    const short* Wg0 = W2T + sn * CC + skg * 8;          // e=0 rows 0..63
    const short* Wg1 = W2T + (64 + sn) * CC + skg * 8;   // e=1 rows 64..127
    short* Ws0 = (short*)w2s + sn * W2S + skg * 8;
    short* Ws1 = (short*)w2s + (64 + sn) * W2S + skg * 8;

    f32x4 acc[8];
    #pragma unroll
    for (int ni = 0; ni < 8; ++ni) acc[ni] = (f32x4){0.f, 0.f, 0.f, 0.f};

    // prologue: stage chunk 0 into buf 0
    {
        bf16x8 r0 = *(const bf16x8*)(Wg0);
        bf16x8 r1 = *(const bf16x8*)(Wg1);
        *(bf16x8*)(Ws0) = r0;
        *(bf16x8*)(Ws1) = r1;
    }
    __syncthreads();

    #pragma unroll
    for (int kt = 0; kt < 8; ++kt) {
        int buf = kt & 1;
        // early: next chunk global -> regs (latency overlapped with gelu/MFMA)
        bf16x8 nx0, nx1;
        if (kt < 7) {
            nx0 = *(const bf16x8*)(Wg0 + (kt + 1) * 32);
            nx1 = *(const bf16x8*)(Wg1 + (kt + 1) * 32);
        }
        // A + Qc loads for this chunk; z1 = gelu(A + Qc) -> bf16 frag
        int k0 = kt * 32 + quad * 8;
        float4 q0 = *(const float4*)(Qrow + k0);
        float4 q1 = *(const float4*)(Qrow + k0 + 4);
        const float* Ap = Abase + (size_t)(kt * 4 + quad) * 128;
        float4 a0 = *(const float4*)(Ap);
        float4 a1 = *(const float4*)(Ap + 4);
        union { bf16x8 v; short s[8]; } u;
        u.s[0] = f2bf(gelu_fast(a0.x + q0.x));
        u.s[1] = f2bf(gelu_fast(a0.y + q0.y));
        u.s[2] = f2bf(gelu_fast(a0.z + q0.z));
        u.s[3] = f2bf(gelu_fast(a0.w + q0.w));
        u.s[4] = f2bf(gelu_fast(a1.x + q1.x));
        u.s[5] = f2bf(gelu_fast(a1.y + q1.y));
        u.s[6] = f2bf(gelu_fast(a1.z + q1.z));
        u.s[7] = f2bf(gelu_fast(a1.w + q1.w));
        #pragma unroll
        for (int ni = 0; ni < 8; ++ni) {
            bf16x8 bfv = *(const bf16x8*)&w2s[buf][(ni * 16 + col16) * W2S + quad * 8];
            acc[ni] = __builtin_amdgcn_mfma_f32_16x16x32_bf16(u.v, bfv, acc[ni], 0, 0, 0);
        }
        if (kt < 7) {
            short* d0 = Ws0 + (1 - buf) * 128 * W2S;
            short* d1 = Ws1 + (1 - buf) * 128 * W2S;
            *(bf16x8*)d0 = nx0;
            *(bf16x8*)d1 = nx1;
            __syncthreads();
        }
    }

    // epilogue: z2 = gelu(acc + b2); logits = z2@W3; reduce over col16; lsm
    float p0[4] = {0, 0, 0, 0}, p1[4] = {0, 0, 0, 0};
    #pragma unroll
    for (int ni = 0; ni < 8; ++ni) {
        int c = ni * 16 + col16;
        float bb = b2[c];
        float2 w3v = *(const float2*)(W3 + c * 2);
        #pragma unroll
        for (int r = 0; r < 4; ++r) {
            float z = gelu_fast(acc[ni][r] + bb);
            p0[r] = fmaf(z, w3v.x, p0[r]);
            p1[r] = fmaf(z, w3v.y, p1[r]);
        }
    }
    float b30 = b3[0], b31 = b3[1];
    #pragma unroll
    for (int r = 0; r < 4; ++r) {
        float s0 = p0[r], s1 = p1[r];
        #pragma unroll
        for (int off = 1; off < 16; off <<= 1) {
            s0 += __shfl_xor(s0, off);
            s1 += __shfl_xor(s1, off);
        }
        if (col16 == 0) {
            float z0 = s0 + b30, z1v = s1 + b31;
            float m = fmaxf(z0, z1v);
            float lse = m + __logf(__expf(z0 - m) + __expf(z1v - m));
            int j = jt * 64 + w * 16 + quad * 4 + r;
            *(float2*)(out + ((size_t)(b * NQ + iq) * NN + j) * 2) =
                make_float2(z0 - lse, z1v - lse);
        }
    }
}

extern "C" void kernel_launch(void* const* d_in, const int* in_sizes, int n_in,
                              void* d_out, int out_size, void* d_ws, size_t ws_size,
                              hipStream_t stream) {
    const float* x      = (const float*)d_in[0];
    const float* query  = (const float*)d_in[1];
    const float* policy = (const float*)d_in[2];
    const float* ln_g   = (const float*)d_in[3];
    const float* ln_b   = (const float*)d_in[4];
    const float* W_in   = (const float*)d_in[5];
    const float* b_in   = (const float*)d_in[6];
    const float* W1     = (const float*)d_in[7];
    const float* b1     = (const float*)d_in[8];
    const float* W2     = (const float*)d_in[9];
    const float* b2     = (const float*)d_in[10];
    const float* W3     = (const float*)d_in[11];
    const float* b3     = (const float*)d_in[12];
    float* out = (float*)d_out;

    float* ws    = (float*)d_ws;
    float* At    = ws;                 // 2*1024*256 fp32 (MFMA-tiled)
    float* Qc    = ws + 524288;        // 200*256
    float* gpart = ws + 575488;        // 512*128
    float* ppart = ws + 641024;        // 512
    short* W2T   = (short*)(ws + 641536);  // 128*256 bf16 (16 KB)

    kA_fused<<<544, 256, 0, stream>>>(x, ln_g, ln_b, W_in, b_in, policy,
                                      W1, W2, At, gpart, ppart, W2T);
    kB_qc<<<BB * NQ, 256, 0, stream>>>(query, W1, gpart, ppart, b1, Qc);
    k5_main<<<BB * NQ * (NN / 64), 256, 0, stream>>>(At, Qc, W2T, b2, W3, b3, out);
}